// Round 1
// baseline (4932.531 us; speedup 1.0000x reference)
//
#include <hip/hip_runtime.h>

#define N_NODES 100000
#define N_EDGES 1600000
#define EPSV 1e-5f

// ---------------- scatter kernels (atomic segment-sum) ----------------

__global__ void scatter_d32(const float* __restrict__ x, const int* __restrict__ ei,
                            float* __restrict__ agg) {
  long long gid = (long long)blockIdx.x * blockDim.x + threadIdx.x;
  int e = (int)(gid >> 3);
  if (e >= N_EDGES) return;
  int c = (int)(gid & 7);
  int src = ei[e];
  int dst = ei[N_EDGES + e];
  const float4 v = *reinterpret_cast<const float4*>(x + (size_t)src * 32 + c * 4);
  float* p = agg + (size_t)dst * 32 + c * 4;
  unsafeAtomicAdd(p + 0, v.x);
  unsafeAtomicAdd(p + 1, v.y);
  unsafeAtomicAdd(p + 2, v.z);
  unsafeAtomicAdd(p + 3, v.w);
}

__global__ void scatter_d64(const float* __restrict__ h, const int* __restrict__ ei,
                            float* __restrict__ agg) {
  long long gid = (long long)blockIdx.x * blockDim.x + threadIdx.x;
  int e = (int)(gid >> 4);
  if (e >= N_EDGES) return;
  int c = (int)(gid & 15);
  int src = ei[e];
  int dst = ei[N_EDGES + e];
  const float4 v = *reinterpret_cast<const float4*>(h + (size_t)src * 64 + c * 4);
  float* p = agg + (size_t)dst * 64 + c * 4;
  unsafeAtomicAdd(p + 0, v.x);
  unsafeAtomicAdd(p + 1, v.y);
  unsafeAtomicAdd(p + 2, v.z);
  unsafeAtomicAdd(p + 3, v.w);
}

__global__ void scatter_d64w(const float* __restrict__ h, const int* __restrict__ ei,
                             const float* __restrict__ ew, float* __restrict__ agg) {
  long long gid = (long long)blockIdx.x * blockDim.x + threadIdx.x;
  int e = (int)(gid >> 4);
  if (e >= N_EDGES) return;
  int c = (int)(gid & 15);
  int src = ei[e];
  int dst = ei[N_EDGES + e];
  float w = ew[e];
  float4 v = *reinterpret_cast<const float4*>(h + (size_t)src * 64 + c * 4);
  float* p = agg + (size_t)dst * 64 + c * 4;
  unsafeAtomicAdd(p + 0, v.x * w);
  unsafeAtomicAdd(p + 1, v.y * w);
  unsafeAtomicAdd(p + 2, v.z * w);
  unsafeAtomicAdd(p + 3, v.w * w);
}

// ---------------- per-node dense kernels ----------------

// h1pre[n][j] = dot32(agg1[n], W1rel[j]) + dot32(x[n], W1root[j]),  j<64
__global__ void node1_kernel(const float* __restrict__ agg, const float* __restrict__ x,
                             const float* __restrict__ Wrel, const float* __restrict__ Wroot,
                             float* __restrict__ out) {
  int n = blockIdx.x * blockDim.x + threadIdx.x;
  if (n >= N_NODES) return;
  float a[32], r[32];
  const float4* ap = reinterpret_cast<const float4*>(agg + (size_t)n * 32);
  const float4* rp = reinterpret_cast<const float4*>(x + (size_t)n * 32);
#pragma unroll
  for (int i = 0; i < 8; ++i) {
    float4 v = ap[i]; a[4*i] = v.x; a[4*i+1] = v.y; a[4*i+2] = v.z; a[4*i+3] = v.w;
    float4 u = rp[i]; r[4*i] = u.x; r[4*i+1] = u.y; r[4*i+2] = u.z; r[4*i+3] = u.w;
  }
  float* op = out + (size_t)n * 64;
  for (int j0 = 0; j0 < 64; j0 += 4) {
    float accs[4];
#pragma unroll
    for (int jj = 0; jj < 4; ++jj) {
      const float* wr = Wrel + (size_t)(j0 + jj) * 32;
      const float* wo = Wroot + (size_t)(j0 + jj) * 32;
      float acc = 0.f;
#pragma unroll
      for (int k = 0; k < 32; ++k) acc = fmaf(a[k], wr[k], fmaf(r[k], wo[k], acc));
      accs[jj] = acc;
    }
    *reinterpret_cast<float4*>(op + j0) = make_float4(accs[0], accs[1], accs[2], accs[3]);
  }
}

// h2pre[n][j] = dot64(agg2[n], W2rel[j]) + dot64(h1[n], W2root[j]),  j<128
__global__ void node2_kernel(const float* __restrict__ agg, const float* __restrict__ h1,
                             const float* __restrict__ Wrel, const float* __restrict__ Wroot,
                             float* __restrict__ out) {
  int n = blockIdx.x * blockDim.x + threadIdx.x;
  if (n >= N_NODES) return;
  float a[64], r[64];
  const float4* ap = reinterpret_cast<const float4*>(agg + (size_t)n * 64);
  const float4* rp = reinterpret_cast<const float4*>(h1 + (size_t)n * 64);
#pragma unroll
  for (int i = 0; i < 16; ++i) {
    float4 v = ap[i]; a[4*i] = v.x; a[4*i+1] = v.y; a[4*i+2] = v.z; a[4*i+3] = v.w;
    float4 u = rp[i]; r[4*i] = u.x; r[4*i+1] = u.y; r[4*i+2] = u.z; r[4*i+3] = u.w;
  }
  float* op = out + (size_t)n * 128;
  for (int j0 = 0; j0 < 128; j0 += 4) {
    float accs[4];
#pragma unroll
    for (int jj = 0; jj < 4; ++jj) {
      const float* wr = Wrel + (size_t)(j0 + jj) * 64;
      const float* wo = Wroot + (size_t)(j0 + jj) * 64;
      float acc = 0.f;
#pragma unroll
      for (int k = 0; k < 64; ++k) acc = fmaf(a[k], wr[k], fmaf(r[k], wo[k], acc));
      accs[jj] = acc;
    }
    *reinterpret_cast<float4*>(op + j0) = make_float4(accs[0], accs[1], accs[2], accs[3]);
  }
}

// h3pre[n][j] = agg3[n][j] + dot128(h2[n], W3root[j]),  j<64
__global__ void node3_kernel(const float* __restrict__ agg3, const float* __restrict__ h2,
                             const float* __restrict__ Wroot, float* __restrict__ out) {
  int n = blockIdx.x * blockDim.x + threadIdx.x;
  if (n >= N_NODES) return;
  float r[128];
  const float4* rp = reinterpret_cast<const float4*>(h2 + (size_t)n * 128);
#pragma unroll
  for (int i = 0; i < 32; ++i) {
    float4 u = rp[i]; r[4*i] = u.x; r[4*i+1] = u.y; r[4*i+2] = u.z; r[4*i+3] = u.w;
  }
  const float* ag = agg3 + (size_t)n * 64;
  float* op = out + (size_t)n * 64;
  for (int j0 = 0; j0 < 64; j0 += 4) {
    float accs[4];
#pragma unroll
    for (int jj = 0; jj < 4; ++jj) {
      const float* wo = Wroot + (size_t)(j0 + jj) * 128;
      float acc = ag[j0 + jj];
#pragma unroll
      for (int k = 0; k < 128; ++k) acc = fmaf(r[k], wo[k], acc);
      accs[jj] = acc;
    }
    *reinterpret_cast<float4*>(op + j0) = make_float4(accs[0], accs[1], accs[2], accs[3]);
  }
}

// ---------------- batchnorm ----------------

template <int D>
__global__ void bn_stats(const float* __restrict__ h, float* __restrict__ sums) {
  const int LANES = 256 / D;
  int j = threadIdx.x & (D - 1);
  int lane = threadIdx.x / D;
  float s = 0.f, ss = 0.f;
  for (int n = blockIdx.x * LANES + lane; n < N_NODES; n += gridDim.x * LANES) {
    float v = h[(size_t)n * D + j];
    s += v; ss += v * v;
  }
  unsafeAtomicAdd(&sums[j], s);
  unsafeAtomicAdd(&sums[D + j], ss);
}

__global__ void bn_finalize(const float* __restrict__ sums, const float* __restrict__ g,
                            const float* __restrict__ be, float* __restrict__ sc,
                            float* __restrict__ sh, int D) {
  int j = threadIdx.x;
  if (j >= D) return;
  const float invN = 1.f / (float)N_NODES;
  float mean = sums[j] * invN;
  float var = sums[D + j] * invN - mean * mean;
  float r = rsqrtf(var + EPSV);
  float scale = g[j] * r;
  sc[j] = scale;
  sh[j] = be[j] - mean * scale;
}

// h[n][j] = relu(hp[n][j]*sc[j] + sh[j]) over N*64, float4-grid
__global__ void bn_apply_relu_d64(const float* __restrict__ hp, const float* __restrict__ sc,
                                  const float* __restrict__ sh, float* __restrict__ h) {
  long long i4 = (long long)blockIdx.x * blockDim.x + threadIdx.x;
  if (i4 * 4 >= (long long)N_NODES * 64) return;
  int j0 = (int)((i4 * 4) & 63);
  float4 v = reinterpret_cast<const float4*>(hp)[i4];
  v.x = fmaxf(fmaf(v.x, sc[j0 + 0], sh[j0 + 0]), 0.f);
  v.y = fmaxf(fmaf(v.y, sc[j0 + 1], sh[j0 + 1]), 0.f);
  v.z = fmaxf(fmaf(v.z, sc[j0 + 2], sh[j0 + 2]), 0.f);
  v.w = fmaxf(fmaf(v.w, sc[j0 + 3], sh[j0 + 3]), 0.f);
  reinterpret_cast<float4*>(h)[i4] = v;
}

// h2 = relu(h2pre*sc+sh) in place; y2[n][j] = dot128(h2[n], W3rel[j]) j<64
__global__ void apply2_y2_kernel(float* __restrict__ h2, const float* __restrict__ sc,
                                 const float* __restrict__ sh, const float* __restrict__ Wrel,
                                 float* __restrict__ y2) {
  int n = blockIdx.x * blockDim.x + threadIdx.x;
  if (n >= N_NODES) return;
  float r[128];
  float4* hp = reinterpret_cast<float4*>(h2 + (size_t)n * 128);
#pragma unroll
  for (int i = 0; i < 32; ++i) {
    float4 u = hp[i];
    int k = 4 * i;
    r[k+0] = fmaxf(fmaf(u.x, sc[k+0], sh[k+0]), 0.f);
    r[k+1] = fmaxf(fmaf(u.y, sc[k+1], sh[k+1]), 0.f);
    r[k+2] = fmaxf(fmaf(u.z, sc[k+2], sh[k+2]), 0.f);
    r[k+3] = fmaxf(fmaf(u.w, sc[k+3], sh[k+3]), 0.f);
    hp[i] = make_float4(r[k+0], r[k+1], r[k+2], r[k+3]);
  }
  float* yp = y2 + (size_t)n * 64;
  for (int j0 = 0; j0 < 64; j0 += 4) {
    float accs[4];
#pragma unroll
    for (int jj = 0; jj < 4; ++jj) {
      const float* wr = Wrel + (size_t)(j0 + jj) * 128;
      float acc = 0.f;
#pragma unroll
      for (int k = 0; k < 128; ++k) acc = fmaf(r[k], wr[k], acc);
      accs[jj] = acc;
    }
    *reinterpret_cast<float4*>(yp + j0) = make_float4(accs[0], accs[1], accs[2], accs[3]);
  }
}

// t = relu(h3pre*sc3+sh3 + h1); c = relu(t@Wc1.T + bc1); out = c@Wc2.T + bc2
__global__ void final_kernel(const float* __restrict__ h3p, const float* __restrict__ h1,
                             const float* __restrict__ sc, const float* __restrict__ sh,
                             const float* __restrict__ Wc1, const float* __restrict__ bc1,
                             const float* __restrict__ Wc2, const float* __restrict__ bc2,
                             float* __restrict__ out) {
  int n = blockIdx.x * blockDim.x + threadIdx.x;
  if (n >= N_NODES) return;
  float t[64];
  const float4* pp = reinterpret_cast<const float4*>(h3p + (size_t)n * 64);
  const float4* hp = reinterpret_cast<const float4*>(h1 + (size_t)n * 64);
#pragma unroll
  for (int i = 0; i < 16; ++i) {
    float4 v = pp[i];
    float4 u = hp[i];
    int k = 4 * i;
    t[k+0] = fmaxf(fmaf(v.x, sc[k+0], sh[k+0]) + u.x, 0.f);
    t[k+1] = fmaxf(fmaf(v.y, sc[k+1], sh[k+1]) + u.y, 0.f);
    t[k+2] = fmaxf(fmaf(v.z, sc[k+2], sh[k+2]) + u.z, 0.f);
    t[k+3] = fmaxf(fmaf(v.w, sc[k+3], sh[k+3]) + u.w, 0.f);
  }
  float c[32];
  for (int j = 0; j < 32; ++j) {
    const float* w = Wc1 + (size_t)j * 64;
    float acc = bc1[j];
#pragma unroll
    for (int k = 0; k < 64; ++k) acc = fmaf(t[k], w[k], acc);
    c[j] = fmaxf(acc, 0.f);
  }
  float o0 = bc2[0], o1 = bc2[1];
#pragma unroll
  for (int j = 0; j < 32; ++j) {
    o0 = fmaf(c[j], Wc2[j], o0);
    o1 = fmaf(c[j], Wc2[32 + j], o1);
  }
  float* op = out + (size_t)n * 2;
  op[0] = o0;
  op[1] = o1;
}

// ---------------- launcher ----------------

extern "C" void kernel_launch(void* const* d_in, const int* in_sizes, int n_in,
                              void* d_out, int out_size, void* d_ws, size_t ws_size,
                              hipStream_t stream) {
  const float* x      = (const float*)d_in[0];
  const int*   ei     = (const int*)d_in[1];
  const float* ew     = (const float*)d_in[2];
  const float* W1rel  = (const float*)d_in[3];
  const float* W1root = (const float*)d_in[5];
  const float* W2rel  = (const float*)d_in[6];
  const float* W2root = (const float*)d_in[8];
  const float* W3rel  = (const float*)d_in[9];
  const float* W3root = (const float*)d_in[11];
  const float* g1  = (const float*)d_in[12];
  const float* be1 = (const float*)d_in[13];
  const float* g2  = (const float*)d_in[14];
  const float* be2 = (const float*)d_in[15];
  const float* g3  = (const float*)d_in[16];
  const float* be3 = (const float*)d_in[17];
  const float* Wc1 = (const float*)d_in[18];
  const float* bc1 = (const float*)d_in[19];
  const float* Wc2 = (const float*)d_in[20];
  const float* bc2 = (const float*)d_in[21];

  float* ws = (float*)d_ws;
  const size_t NF = (size_t)N_NODES * 64;
  float* A = ws;            // agg1 (N*32), later y2 (N*64)
  float* B = ws + NF;       // h1pre (N*64), later agg3 (N*64)
  float* C = ws + 2 * NF;   // h1 (N*64), live to the end
  float* D = ws + 3 * NF;   // agg2 (N*64), later h3pre (N*64)
  float* E = ws + 4 * NF;   // h2pre/h2 in-place (N*128)
  float* S = ws + 6 * NF;   // stats: 1024 floats
  // S layout: L1 sums @0 (128), sc1 @128, sh1 @192; L2 sums @256 (256), sc2 @512, sh2 @640;
  //           L3 sums @768 (128), sc3 @896, sh3 @960

  hipMemsetAsync(A, 0, (size_t)N_NODES * 32 * sizeof(float), stream);  // agg1
  hipMemsetAsync(D, 0, NF * sizeof(float), stream);                    // agg2
  hipMemsetAsync(S, 0, 1024 * sizeof(float), stream);                  // all BN sums

  const int nodeBlocks = (N_NODES + 255) / 256;

  // ---- layer 1 ----
  scatter_d32<<<(N_EDGES * 8 + 255) / 256, 256, 0, stream>>>(x, ei, A);
  node1_kernel<<<nodeBlocks, 256, 0, stream>>>(A, x, W1rel, W1root, B);
  bn_stats<64><<<128, 256, 0, stream>>>(B, S);
  bn_finalize<<<1, 128, 0, stream>>>(S, g1, be1, S + 128, S + 192, 64);
  bn_apply_relu_d64<<<(int)((NF / 4 + 255) / 256), 256, 0, stream>>>(B, S + 128, S + 192, C);

  // ---- layer 2 ----
  scatter_d64<<<(N_EDGES * 16 + 255) / 256, 256, 0, stream>>>(C, ei, D);
  node2_kernel<<<nodeBlocks, 256, 0, stream>>>(D, C, W2rel, W2root, E);
  bn_stats<128><<<128, 256, 0, stream>>>(E, S + 256);
  bn_finalize<<<1, 128, 0, stream>>>(S + 256, g2, be2, S + 512, S + 640, 128);
  apply2_y2_kernel<<<nodeBlocks, 256, 0, stream>>>(E, S + 512, S + 640, W3rel, A);  // y2 -> A

  // ---- layer 3 ----
  hipMemsetAsync(B, 0, NF * sizeof(float), stream);  // agg3 (h1pre is dead)
  scatter_d64w<<<(N_EDGES * 16 + 255) / 256, 256, 0, stream>>>(A, ei, ew, B);
  node3_kernel<<<nodeBlocks, 256, 0, stream>>>(B, E, W3root, D);  // h3pre -> D
  bn_stats<64><<<128, 256, 0, stream>>>(D, S + 768);
  bn_finalize<<<1, 128, 0, stream>>>(S + 768, g3, be3, S + 896, S + 960, 64);

  // ---- residual + classifier ----
  final_kernel<<<nodeBlocks, 256, 0, stream>>>(D, C, S + 896, S + 960, Wc1, bc1, Wc2, bc2,
                                               (float*)d_out);
}

// Round 2
// 2137.052 us; speedup vs baseline: 2.3081x; 2.3081x over previous
//
#include <hip/hip_runtime.h>

#define N_NODES 100000
#define N_EDGES 1600000
#define EPSV 1e-5f

// ---------------- CSR-by-destination build ----------------

__global__ void hist_kernel(const int* __restrict__ ei, int* __restrict__ cnt) {
  int e = blockIdx.x * blockDim.x + threadIdx.x;
  if (e >= N_EDGES) return;
  atomicAdd(&cnt[ei[N_EDGES + e]], 1);
}

#define SCAN_T 1024
__global__ void scan_kernel(const int* __restrict__ cnt, int* __restrict__ rowptr,
                            int* __restrict__ cursor) {
  __shared__ int part[SCAN_T];
  int tid = threadIdx.x;
  const int CH = (N_NODES + SCAN_T - 1) / SCAN_T;  // 98
  int beg = tid * CH;
  int end = min(beg + CH, N_NODES);
  int s = 0;
  for (int i = beg; i < end; ++i) s += cnt[i];
  part[tid] = s;
  __syncthreads();
  for (int d = 1; d < SCAN_T; d <<= 1) {
    int v = (tid >= d) ? part[tid - d] : 0;
    __syncthreads();
    part[tid] += v;
    __syncthreads();
  }
  int off = part[tid] - s;  // exclusive prefix
  for (int i = beg; i < end; ++i) {
    rowptr[i] = off;
    cursor[i] = off;
    off += cnt[i];
  }
  if (tid == SCAN_T - 1) rowptr[N_NODES] = off;
}

__global__ void fill_kernel(const int* __restrict__ ei, const float* __restrict__ ew,
                            int* __restrict__ cursor, int* __restrict__ col_src,
                            float* __restrict__ col_w) {
  int e = blockIdx.x * blockDim.x + threadIdx.x;
  if (e >= N_EDGES) return;
  int d = ei[N_EDGES + e];
  int p = atomicAdd(&cursor[d], 1);
  col_src[p] = ei[e];
  col_w[p] = ew[e];
}

// ---------------- gather-side segment sums ----------------

// 8 lanes per node, each owns 4 of 32 features
__global__ void gather_d32(const float* __restrict__ x, const int* __restrict__ rowptr,
                           const int* __restrict__ col_src, float* __restrict__ agg) {
  int gid = blockIdx.x * blockDim.x + threadIdx.x;
  int n = gid >> 3;
  if (n >= N_NODES) return;
  int c = gid & 7;
  int beg = rowptr[n], end = rowptr[n + 1];
  float4 acc = make_float4(0.f, 0.f, 0.f, 0.f);
  for (int p = beg; p < end; ++p) {
    int src = col_src[p];
    float4 v = *reinterpret_cast<const float4*>(x + (size_t)src * 32 + c * 4);
    acc.x += v.x; acc.y += v.y; acc.z += v.z; acc.w += v.w;
  }
  *reinterpret_cast<float4*>(agg + (size_t)n * 32 + c * 4) = acc;
}

// 16 lanes per node, each owns 4 of 64 features
template <bool WEIGHTED>
__global__ void gather_d64(const float* __restrict__ h, const int* __restrict__ rowptr,
                           const int* __restrict__ col_src, const float* __restrict__ col_w,
                           float* __restrict__ agg) {
  int gid = blockIdx.x * blockDim.x + threadIdx.x;
  int n = gid >> 4;
  if (n >= N_NODES) return;
  int c = gid & 15;
  int beg = rowptr[n], end = rowptr[n + 1];
  float4 acc = make_float4(0.f, 0.f, 0.f, 0.f);
  for (int p = beg; p < end; ++p) {
    int src = col_src[p];
    float4 v = *reinterpret_cast<const float4*>(h + (size_t)src * 64 + c * 4);
    if (WEIGHTED) {
      float w = col_w[p];
      acc.x = fmaf(v.x, w, acc.x); acc.y = fmaf(v.y, w, acc.y);
      acc.z = fmaf(v.z, w, acc.z); acc.w = fmaf(v.w, w, acc.w);
    } else {
      acc.x += v.x; acc.y += v.y; acc.z += v.z; acc.w += v.w;
    }
  }
  *reinterpret_cast<float4*>(agg + (size_t)n * 64 + c * 4) = acc;
}

// ---------------- per-node dense kernels ----------------

__global__ void node1_kernel(const float* __restrict__ agg, const float* __restrict__ x,
                             const float* __restrict__ Wrel, const float* __restrict__ Wroot,
                             float* __restrict__ out) {
  int n = blockIdx.x * blockDim.x + threadIdx.x;
  if (n >= N_NODES) return;
  float a[32], r[32];
  const float4* ap = reinterpret_cast<const float4*>(agg + (size_t)n * 32);
  const float4* rp = reinterpret_cast<const float4*>(x + (size_t)n * 32);
#pragma unroll
  for (int i = 0; i < 8; ++i) {
    float4 v = ap[i]; a[4*i] = v.x; a[4*i+1] = v.y; a[4*i+2] = v.z; a[4*i+3] = v.w;
    float4 u = rp[i]; r[4*i] = u.x; r[4*i+1] = u.y; r[4*i+2] = u.z; r[4*i+3] = u.w;
  }
  float* op = out + (size_t)n * 64;
  for (int j0 = 0; j0 < 64; j0 += 4) {
    float accs[4];
#pragma unroll
    for (int jj = 0; jj < 4; ++jj) {
      const float* wr = Wrel + (size_t)(j0 + jj) * 32;
      const float* wo = Wroot + (size_t)(j0 + jj) * 32;
      float acc = 0.f;
#pragma unroll
      for (int k = 0; k < 32; ++k) acc = fmaf(a[k], wr[k], fmaf(r[k], wo[k], acc));
      accs[jj] = acc;
    }
    *reinterpret_cast<float4*>(op + j0) = make_float4(accs[0], accs[1], accs[2], accs[3]);
  }
}

__global__ void node2_kernel(const float* __restrict__ agg, const float* __restrict__ h1,
                             const float* __restrict__ Wrel, const float* __restrict__ Wroot,
                             float* __restrict__ out) {
  int n = blockIdx.x * blockDim.x + threadIdx.x;
  if (n >= N_NODES) return;
  float a[64], r[64];
  const float4* ap = reinterpret_cast<const float4*>(agg + (size_t)n * 64);
  const float4* rp = reinterpret_cast<const float4*>(h1 + (size_t)n * 64);
#pragma unroll
  for (int i = 0; i < 16; ++i) {
    float4 v = ap[i]; a[4*i] = v.x; a[4*i+1] = v.y; a[4*i+2] = v.z; a[4*i+3] = v.w;
    float4 u = rp[i]; r[4*i] = u.x; r[4*i+1] = u.y; r[4*i+2] = u.z; r[4*i+3] = u.w;
  }
  float* op = out + (size_t)n * 128;
  for (int j0 = 0; j0 < 128; j0 += 4) {
    float accs[4];
#pragma unroll
    for (int jj = 0; jj < 4; ++jj) {
      const float* wr = Wrel + (size_t)(j0 + jj) * 64;
      const float* wo = Wroot + (size_t)(j0 + jj) * 64;
      float acc = 0.f;
#pragma unroll
      for (int k = 0; k < 64; ++k) acc = fmaf(a[k], wr[k], fmaf(r[k], wo[k], acc));
      accs[jj] = acc;
    }
    *reinterpret_cast<float4*>(op + j0) = make_float4(accs[0], accs[1], accs[2], accs[3]);
  }
}

__global__ void node3_kernel(const float* __restrict__ agg3, const float* __restrict__ h2,
                             const float* __restrict__ Wroot, float* __restrict__ out) {
  int n = blockIdx.x * blockDim.x + threadIdx.x;
  if (n >= N_NODES) return;
  float r[128];
  const float4* rp = reinterpret_cast<const float4*>(h2 + (size_t)n * 128);
#pragma unroll
  for (int i = 0; i < 32; ++i) {
    float4 u = rp[i]; r[4*i] = u.x; r[4*i+1] = u.y; r[4*i+2] = u.z; r[4*i+3] = u.w;
  }
  const float* ag = agg3 + (size_t)n * 64;
  float* op = out + (size_t)n * 64;
  for (int j0 = 0; j0 < 64; j0 += 4) {
    float accs[4];
#pragma unroll
    for (int jj = 0; jj < 4; ++jj) {
      const float* wo = Wroot + (size_t)(j0 + jj) * 128;
      float acc = ag[j0 + jj];
#pragma unroll
      for (int k = 0; k < 128; ++k) acc = fmaf(r[k], wo[k], acc);
      accs[jj] = acc;
    }
    *reinterpret_cast<float4*>(op + j0) = make_float4(accs[0], accs[1], accs[2], accs[3]);
  }
}

// ---------------- batchnorm ----------------

template <int D>
__global__ void bn_stats(const float* __restrict__ h, float* __restrict__ sums) {
  const int LANES = 256 / D;
  int j = threadIdx.x & (D - 1);
  int lane = threadIdx.x / D;
  float s = 0.f, ss = 0.f;
  for (int n = blockIdx.x * LANES + lane; n < N_NODES; n += gridDim.x * LANES) {
    float v = h[(size_t)n * D + j];
    s += v; ss += v * v;
  }
  unsafeAtomicAdd(&sums[j], s);
  unsafeAtomicAdd(&sums[D + j], ss);
}

__global__ void bn_finalize(const float* __restrict__ sums, const float* __restrict__ g,
                            const float* __restrict__ be, float* __restrict__ sc,
                            float* __restrict__ sh, int D) {
  int j = threadIdx.x;
  if (j >= D) return;
  const float invN = 1.f / (float)N_NODES;
  float mean = sums[j] * invN;
  float var = sums[D + j] * invN - mean * mean;
  float r = rsqrtf(var + EPSV);
  float scale = g[j] * r;
  sc[j] = scale;
  sh[j] = be[j] - mean * scale;
}

__global__ void bn_apply_relu_d64(const float* __restrict__ hp, const float* __restrict__ sc,
                                  const float* __restrict__ sh, float* __restrict__ h) {
  long long i4 = (long long)blockIdx.x * blockDim.x + threadIdx.x;
  if (i4 * 4 >= (long long)N_NODES * 64) return;
  int j0 = (int)((i4 * 4) & 63);
  float4 v = reinterpret_cast<const float4*>(hp)[i4];
  v.x = fmaxf(fmaf(v.x, sc[j0 + 0], sh[j0 + 0]), 0.f);
  v.y = fmaxf(fmaf(v.y, sc[j0 + 1], sh[j0 + 1]), 0.f);
  v.z = fmaxf(fmaf(v.z, sc[j0 + 2], sh[j0 + 2]), 0.f);
  v.w = fmaxf(fmaf(v.w, sc[j0 + 3], sh[j0 + 3]), 0.f);
  reinterpret_cast<float4*>(h)[i4] = v;
}

// h2 = relu(h2pre*sc+sh) in place; y2[n][j] = dot128(h2[n], W3rel[j]) j<64
__global__ void apply2_y2_kernel(float* __restrict__ h2, const float* __restrict__ sc,
                                 const float* __restrict__ sh, const float* __restrict__ Wrel,
                                 float* __restrict__ y2) {
  int n = blockIdx.x * blockDim.x + threadIdx.x;
  if (n >= N_NODES) return;
  float r[128];
  float4* hp = reinterpret_cast<float4*>(h2 + (size_t)n * 128);
#pragma unroll
  for (int i = 0; i < 32; ++i) {
    float4 u = hp[i];
    int k = 4 * i;
    r[k+0] = fmaxf(fmaf(u.x, sc[k+0], sh[k+0]), 0.f);
    r[k+1] = fmaxf(fmaf(u.y, sc[k+1], sh[k+1]), 0.f);
    r[k+2] = fmaxf(fmaf(u.z, sc[k+2], sh[k+2]), 0.f);
    r[k+3] = fmaxf(fmaf(u.w, sc[k+3], sh[k+3]), 0.f);
    hp[i] = make_float4(r[k+0], r[k+1], r[k+2], r[k+3]);
  }
  float* yp = y2 + (size_t)n * 64;
  for (int j0 = 0; j0 < 64; j0 += 4) {
    float accs[4];
#pragma unroll
    for (int jj = 0; jj < 4; ++jj) {
      const float* wr = Wrel + (size_t)(j0 + jj) * 128;
      float acc = 0.f;
#pragma unroll
      for (int k = 0; k < 128; ++k) acc = fmaf(r[k], wr[k], acc);
      accs[jj] = acc;
    }
    *reinterpret_cast<float4*>(yp + j0) = make_float4(accs[0], accs[1], accs[2], accs[3]);
  }
}

// t = relu(h3pre*sc3+sh3 + h1); c = relu(t@Wc1.T + bc1); out = c@Wc2.T + bc2
__global__ void final_kernel(const float* __restrict__ h3p, const float* __restrict__ h1,
                             const float* __restrict__ sc, const float* __restrict__ sh,
                             const float* __restrict__ Wc1, const float* __restrict__ bc1,
                             const float* __restrict__ Wc2, const float* __restrict__ bc2,
                             float* __restrict__ out) {
  int n = blockIdx.x * blockDim.x + threadIdx.x;
  if (n >= N_NODES) return;
  float t[64];
  const float4* pp = reinterpret_cast<const float4*>(h3p + (size_t)n * 64);
  const float4* hp = reinterpret_cast<const float4*>(h1 + (size_t)n * 64);
#pragma unroll
  for (int i = 0; i < 16; ++i) {
    float4 v = pp[i];
    float4 u = hp[i];
    int k = 4 * i;
    t[k+0] = fmaxf(fmaf(v.x, sc[k+0], sh[k+0]) + u.x, 0.f);
    t[k+1] = fmaxf(fmaf(v.y, sc[k+1], sh[k+1]) + u.y, 0.f);
    t[k+2] = fmaxf(fmaf(v.z, sc[k+2], sh[k+2]) + u.z, 0.f);
    t[k+3] = fmaxf(fmaf(v.w, sc[k+3], sh[k+3]) + u.w, 0.f);
  }
  float c[32];
  for (int j = 0; j < 32; ++j) {
    const float* w = Wc1 + (size_t)j * 64;
    float acc = bc1[j];
#pragma unroll
    for (int k = 0; k < 64; ++k) acc = fmaf(t[k], w[k], acc);
    c[j] = fmaxf(acc, 0.f);
  }
  float o0 = bc2[0], o1 = bc2[1];
#pragma unroll
  for (int j = 0; j < 32; ++j) {
    o0 = fmaf(c[j], Wc2[j], o0);
    o1 = fmaf(c[j], Wc2[32 + j], o1);
  }
  float* op = out + (size_t)n * 2;
  op[0] = o0;
  op[1] = o1;
}

// ---------------- launcher ----------------

extern "C" void kernel_launch(void* const* d_in, const int* in_sizes, int n_in,
                              void* d_out, int out_size, void* d_ws, size_t ws_size,
                              hipStream_t stream) {
  const float* x      = (const float*)d_in[0];
  const int*   ei     = (const int*)d_in[1];
  const float* ew     = (const float*)d_in[2];
  const float* W1rel  = (const float*)d_in[3];
  const float* W1root = (const float*)d_in[5];
  const float* W2rel  = (const float*)d_in[6];
  const float* W2root = (const float*)d_in[8];
  const float* W3rel  = (const float*)d_in[9];
  const float* W3root = (const float*)d_in[11];
  const float* g1  = (const float*)d_in[12];
  const float* be1 = (const float*)d_in[13];
  const float* g2  = (const float*)d_in[14];
  const float* be2 = (const float*)d_in[15];
  const float* g3  = (const float*)d_in[16];
  const float* be3 = (const float*)d_in[17];
  const float* Wc1 = (const float*)d_in[18];
  const float* bc1 = (const float*)d_in[19];
  const float* Wc2 = (const float*)d_in[20];
  const float* bc2 = (const float*)d_in[21];

  float* ws = (float*)d_ws;
  const size_t NF = (size_t)N_NODES * 64;
  // Buffer plan (liveness-packed):
  float* A = ws;            // agg1 (N*32) -> agg2 (N*64) -> agg3 (N*64)
  float* B = ws + NF;       // h1pre -> y2 -> h3pre (each N*64)
  float* C = ws + 2 * NF;   // h1 (N*64), live to the end
  float* E = ws + 3 * NF;   // h2pre/h2 in place (N*128)
  float* X = ws + 5 * NF;   // extras
  float* S = X;                              // 1024 floats of BN stats
  int* rowptr  = (int*)(X + 1024);           // N+1 (pad to N+2)
  int* cnt     = rowptr + (N_NODES + 2);     // N  (histogram)
  int* cursor  = cnt + N_NODES;              // N  (fill cursors)
  int* col_src = cursor + N_NODES;           // E
  float* col_w = (float*)(col_src + N_EDGES);// E
  // S layout: L1 sums @0 (128), sc1 @128, sh1 @192; L2 sums @256 (256), sc2 @512,
  //           sh2 @640; L3 sums @768 (128), sc3 @896, sh3 @960

  hipMemsetAsync(S, 0, 1024 * sizeof(float), stream);
  hipMemsetAsync(cnt, 0, N_NODES * sizeof(int), stream);

  const int nodeBlocks = (N_NODES + 255) / 256;
  const int edgeBlocks = (N_EDGES + 255) / 256;

  // ---- CSR build (by destination) ----
  hist_kernel<<<edgeBlocks, 256, 0, stream>>>(ei, cnt);
  scan_kernel<<<1, SCAN_T, 0, stream>>>(cnt, rowptr, cursor);
  fill_kernel<<<edgeBlocks, 256, 0, stream>>>(ei, ew, cursor, col_src, col_w);

  // ---- layer 1 ----
  gather_d32<<<(N_NODES * 8 + 255) / 256, 256, 0, stream>>>(x, rowptr, col_src, A);
  node1_kernel<<<nodeBlocks, 256, 0, stream>>>(A, x, W1rel, W1root, B);
  bn_stats<64><<<128, 256, 0, stream>>>(B, S);
  bn_finalize<<<1, 128, 0, stream>>>(S, g1, be1, S + 128, S + 192, 64);
  bn_apply_relu_d64<<<(int)((NF / 4 + 255) / 256), 256, 0, stream>>>(B, S + 128, S + 192, C);

  // ---- layer 2 ----
  gather_d64<false><<<(N_NODES * 16 + 255) / 256, 256, 0, stream>>>(C, rowptr, col_src, col_w, A);
  node2_kernel<<<nodeBlocks, 256, 0, stream>>>(A, C, W2rel, W2root, E);
  bn_stats<128><<<128, 256, 0, stream>>>(E, S + 256);
  bn_finalize<<<1, 128, 0, stream>>>(S + 256, g2, be2, S + 512, S + 640, 128);
  apply2_y2_kernel<<<nodeBlocks, 256, 0, stream>>>(E, S + 512, S + 640, W3rel, B);  // y2 -> B

  // ---- layer 3 (aggregate y2 = h2 @ W3rel.T at d=64, algebraically equal) ----
  gather_d64<true><<<(N_NODES * 16 + 255) / 256, 256, 0, stream>>>(B, rowptr, col_src, col_w, A);
  node3_kernel<<<nodeBlocks, 256, 0, stream>>>(A, E, W3root, B);  // h3pre -> B (y2 dead)
  bn_stats<64><<<128, 256, 0, stream>>>(B, S + 768);
  bn_finalize<<<1, 128, 0, stream>>>(S + 768, g3, be3, S + 896, S + 960, 64);

  // ---- residual + classifier ----
  final_kernel<<<nodeBlocks, 256, 0, stream>>>(B, C, S + 896, S + 960, Wc1, bc1, Wc2, bc2,
                                               (float*)d_out);
}

// Round 3
// 1016.169 us; speedup vs baseline: 4.8540x; 2.1030x over previous
//
#include <hip/hip_runtime.h>

#define N_NODES 100000
#define N_EDGES 1600000
#define EPSV 1e-5f

// ---------------- CSR-by-destination build ----------------

__global__ void hist_kernel(const int* __restrict__ ei, int* __restrict__ cnt) {
  int e = blockIdx.x * blockDim.x + threadIdx.x;
  if (e >= N_EDGES) return;
  atomicAdd(&cnt[ei[N_EDGES + e]], 1);
}

#define SCAN_T 1024
__global__ void scan_kernel(const int* __restrict__ cnt, int* __restrict__ rowptr,
                            int* __restrict__ cursor) {
  __shared__ int part[SCAN_T];
  int tid = threadIdx.x;
  const int CH = (N_NODES + SCAN_T - 1) / SCAN_T;
  int beg = tid * CH;
  int end = min(beg + CH, N_NODES);
  int s = 0;
  for (int i = beg; i < end; ++i) s += cnt[i];
  part[tid] = s;
  __syncthreads();
  for (int d = 1; d < SCAN_T; d <<= 1) {
    int v = (tid >= d) ? part[tid - d] : 0;
    __syncthreads();
    part[tid] += v;
    __syncthreads();
  }
  int off = part[tid] - s;
  for (int i = beg; i < end; ++i) {
    rowptr[i] = off;
    cursor[i] = off;
    off += cnt[i];
  }
  if (tid == SCAN_T - 1) rowptr[N_NODES] = off;
}

__global__ void fill_kernel(const int* __restrict__ ei, const float* __restrict__ ew,
                            int* __restrict__ cursor, int* __restrict__ col_src,
                            float* __restrict__ col_w) {
  int e = blockIdx.x * blockDim.x + threadIdx.x;
  if (e >= N_EDGES) return;
  int d = ei[N_EDGES + e];
  int p = atomicAdd(&cursor[d], 1);
  col_src[p] = ei[e];
  col_w[p] = ew[e];
}

// ---------------- gather-side segment sums ----------------

__global__ void gather_d32(const float* __restrict__ x, const int* __restrict__ rowptr,
                           const int* __restrict__ col_src, float* __restrict__ agg) {
  int gid = blockIdx.x * blockDim.x + threadIdx.x;
  int n = gid >> 3;
  if (n >= N_NODES) return;
  int c = gid & 7;
  int beg = rowptr[n], end = rowptr[n + 1];
  float4 acc = make_float4(0.f, 0.f, 0.f, 0.f);
  for (int p = beg; p < end; ++p) {
    int src = col_src[p];
    float4 v = *reinterpret_cast<const float4*>(x + (size_t)src * 32 + c * 4);
    acc.x += v.x; acc.y += v.y; acc.z += v.z; acc.w += v.w;
  }
  *reinterpret_cast<float4*>(agg + (size_t)n * 32 + c * 4) = acc;
}

template <bool WEIGHTED>
__global__ void gather_d64(const float* __restrict__ h, const int* __restrict__ rowptr,
                           const int* __restrict__ col_src, const float* __restrict__ col_w,
                           float* __restrict__ agg) {
  int gid = blockIdx.x * blockDim.x + threadIdx.x;
  int n = gid >> 4;
  if (n >= N_NODES) return;
  int c = gid & 15;
  int beg = rowptr[n], end = rowptr[n + 1];
  float4 acc = make_float4(0.f, 0.f, 0.f, 0.f);
  for (int p = beg; p < end; ++p) {
    int src = col_src[p];
    float4 v = *reinterpret_cast<const float4*>(h + (size_t)src * 64 + c * 4);
    if (WEIGHTED) {
      float w = col_w[p];
      acc.x = fmaf(v.x, w, acc.x); acc.y = fmaf(v.y, w, acc.y);
      acc.z = fmaf(v.z, w, acc.z); acc.w = fmaf(v.w, w, acc.w);
    } else {
      acc.x += v.x; acc.y += v.y; acc.z += v.z; acc.w += v.w;
    }
  }
  *reinterpret_cast<float4*>(agg + (size_t)n * 64 + c * 4) = acc;
}

// ---------------- LDS-tiled node GEMM ----------------
// out[M x DO] = [A1 | A2] @ [W1 ; W2]^T   (concat along K)
// MODE 0: plain.  MODE 1: += R (epilogue).  MODE 2: BN+relu A1 on the fly
// during staging (sc,sh), also write transformed A back to h2act.
// Block: 64 nodes, 256 threads (tx 0..15 -> 4 outputs per j-block,
// ty 0..15 -> 4 nodes). K streamed in 64-wide chunks.

template <int K1, int K2, int DO, int MODE>
__global__ __launch_bounds__(256) void gemm_node(
    const float* __restrict__ A1, const float* __restrict__ A2,
    const float* __restrict__ W1, const float* __restrict__ W2,
    const float* __restrict__ sc, const float* __restrict__ sh,
    const float* __restrict__ R, float* __restrict__ out,
    float* h2act) {
  constexpr int K = K1 + K2;
  constexpr int NC = K / 64;
  constexpr int NJB = DO / 64;
  __shared__ __align__(16) float A_lds[64][68];
  __shared__ __align__(16) float W_lds[64][DO + 4];

  const int tid = threadIdx.x;
  const int tx = tid & 15, ty = tid >> 4;
  const int nbase = blockIdx.x * 64;

  float4 acc[4][NJB];
#pragma unroll
  for (int i = 0; i < 4; ++i)
#pragma unroll
    for (int jb = 0; jb < NJB; ++jb) acc[i][jb] = make_float4(0.f, 0.f, 0.f, 0.f);

#pragma unroll 1
  for (int c = 0; c < NC; ++c) {
    const int kb = c * 64;
    if (c) __syncthreads();
    // ---- stage A tile (64 nodes x 64 k), node-major ----
#pragma unroll
    for (int it = 0; it < 4; ++it) {
      int idx = it * 256 + tid;
      int nl = idx >> 4;
      int kq = (idx & 15) * 4;
      int k = kb + kq;
      int ng = nbase + nl;
      float4 v = make_float4(0.f, 0.f, 0.f, 0.f);
      if (ng < N_NODES) {
        if (K2 == 0 || k < K1)
          v = *reinterpret_cast<const float4*>(A1 + (size_t)ng * K1 + k);
        else
          v = *reinterpret_cast<const float4*>(A2 + (size_t)ng * K2 + (k - K1));
      }
      if (MODE == 2) {
        float4 s4 = *reinterpret_cast<const float4*>(sc + k);
        float4 h4 = *reinterpret_cast<const float4*>(sh + k);
        v.x = fmaxf(fmaf(v.x, s4.x, h4.x), 0.f);
        v.y = fmaxf(fmaf(v.y, s4.y, h4.y), 0.f);
        v.z = fmaxf(fmaf(v.z, s4.z, h4.z), 0.f);
        v.w = fmaxf(fmaf(v.w, s4.w, h4.w), 0.f);
        if (ng < N_NODES)
          *reinterpret_cast<float4*>(h2act + (size_t)ng * K1 + k) = v;
      }
      *reinterpret_cast<float4*>(&A_lds[nl][kq]) = v;
    }
    // ---- stage W chunk (64 k x DO j), k-major ----
#pragma unroll
    for (int it = 0; it < DO / 4; ++it) {
      int idx = it * 256 + tid;
      int j = idx >> 6;
      int kl = idx & 63;
      int k = kb + kl;
      float w;
      if (K2 == 0 || k < K1) w = W1[(size_t)j * K1 + k];
      else w = W2[(size_t)j * K2 + (k - K1)];
      W_lds[kl][j] = w;
    }
    __syncthreads();
    // ---- compute ----
#pragma unroll 4
    for (int k4 = 0; k4 < 16; ++k4) {
      float4 a[4];
#pragma unroll
      for (int i = 0; i < 4; ++i)
        a[i] = *reinterpret_cast<const float4*>(&A_lds[ty * 4 + i][k4 * 4]);
#pragma unroll
      for (int q = 0; q < 4; ++q) {
#pragma unroll
        for (int jb = 0; jb < NJB; ++jb) {
          float4 w = *reinterpret_cast<const float4*>(&W_lds[k4 * 4 + q][jb * 64 + tx * 4]);
#pragma unroll
          for (int i = 0; i < 4; ++i) {
            float av = reinterpret_cast<const float*>(&a[i])[q];
            acc[i][jb].x = fmaf(av, w.x, acc[i][jb].x);
            acc[i][jb].y = fmaf(av, w.y, acc[i][jb].y);
            acc[i][jb].z = fmaf(av, w.z, acc[i][jb].z);
            acc[i][jb].w = fmaf(av, w.w, acc[i][jb].w);
          }
        }
      }
    }
  }
  // ---- epilogue ----
#pragma unroll
  for (int i = 0; i < 4; ++i) {
    int ng = nbase + ty * 4 + i;
    if (ng >= N_NODES) continue;
#pragma unroll
    for (int jb = 0; jb < NJB; ++jb) {
      float4 r = acc[i][jb];
      if (MODE == 1) {
        float4 rr = *reinterpret_cast<const float4*>(R + (size_t)ng * DO + jb * 64 + tx * 4);
        r.x += rr.x; r.y += rr.y; r.z += rr.z; r.w += rr.w;
      }
      *reinterpret_cast<float4*>(out + (size_t)ng * DO + jb * 64 + tx * 4) = r;
    }
  }
}

// ---------------- batchnorm ----------------

template <int D>
__global__ void bn_stats(const float* __restrict__ h, float* __restrict__ sums) {
  const int LANES = 256 / D;
  int j = threadIdx.x & (D - 1);
  int lane = threadIdx.x / D;
  float s = 0.f, ss = 0.f;
  for (int n = blockIdx.x * LANES + lane; n < N_NODES; n += gridDim.x * LANES) {
    float v = h[(size_t)n * D + j];
    s += v; ss += v * v;
  }
  unsafeAtomicAdd(&sums[j], s);
  unsafeAtomicAdd(&sums[D + j], ss);
}

__global__ void bn_finalize(const float* __restrict__ sums, const float* __restrict__ g,
                            const float* __restrict__ be, float* __restrict__ sc,
                            float* __restrict__ sh, int D) {
  int j = threadIdx.x;
  if (j >= D) return;
  const float invN = 1.f / (float)N_NODES;
  float mean = sums[j] * invN;
  float var = sums[D + j] * invN - mean * mean;
  float r = rsqrtf(var + EPSV);
  float scale = g[j] * r;
  sc[j] = scale;
  sh[j] = be[j] - mean * scale;
}

__global__ void bn_apply_relu_d64(const float* __restrict__ hp, const float* __restrict__ sc,
                                  const float* __restrict__ sh, float* __restrict__ h) {
  long long i4 = (long long)blockIdx.x * blockDim.x + threadIdx.x;
  if (i4 * 4 >= (long long)N_NODES * 64) return;
  int j0 = (int)((i4 * 4) & 63);
  float4 v = reinterpret_cast<const float4*>(hp)[i4];
  v.x = fmaxf(fmaf(v.x, sc[j0 + 0], sh[j0 + 0]), 0.f);
  v.y = fmaxf(fmaf(v.y, sc[j0 + 1], sh[j0 + 1]), 0.f);
  v.z = fmaxf(fmaf(v.z, sc[j0 + 2], sh[j0 + 2]), 0.f);
  v.w = fmaxf(fmaf(v.w, sc[j0 + 3], sh[j0 + 3]), 0.f);
  reinterpret_cast<float4*>(h)[i4] = v;
}

// ---------------- fused residual + classifier ----------------
// t = relu(bn3(h3p) + h1); c = relu(t@Wc1^T + bc1); out = c@Wc2^T + bc2

__global__ __launch_bounds__(256) void final_fused(
    const float* __restrict__ h3p, const float* __restrict__ h1,
    const float* __restrict__ sc, const float* __restrict__ sh,
    const float* __restrict__ Wc1, const float* __restrict__ bc1,
    const float* __restrict__ Wc2, const float* __restrict__ bc2,
    float* __restrict__ out) {
  __shared__ __align__(16) float t_lds[64][68];
  __shared__ __align__(16) float w1_lds[64][36];
  __shared__ __align__(16) float c_lds[64][36];
  __shared__ __align__(16) float w2_lds[64];
  __shared__ __align__(16) float b1_lds[32];
  __shared__ float b2_lds[2];
  const int tid = threadIdx.x;
  const int nbase = blockIdx.x * 64;

  // stage t (64 nodes x 64)
#pragma unroll
  for (int it = 0; it < 4; ++it) {
    int idx = it * 256 + tid;
    int nl = idx >> 4;
    int k = (idx & 15) * 4;
    int ng = nbase + nl;
    float4 v = make_float4(0.f, 0.f, 0.f, 0.f);
    if (ng < N_NODES) {
      float4 p = *reinterpret_cast<const float4*>(h3p + (size_t)ng * 64 + k);
      float4 u = *reinterpret_cast<const float4*>(h1 + (size_t)ng * 64 + k);
      float4 s4 = *reinterpret_cast<const float4*>(sc + k);
      float4 h4 = *reinterpret_cast<const float4*>(sh + k);
      v.x = fmaxf(fmaf(p.x, s4.x, h4.x) + u.x, 0.f);
      v.y = fmaxf(fmaf(p.y, s4.y, h4.y) + u.y, 0.f);
      v.z = fmaxf(fmaf(p.z, s4.z, h4.z) + u.z, 0.f);
      v.w = fmaxf(fmaf(p.w, s4.w, h4.w) + u.w, 0.f);
    }
    *reinterpret_cast<float4*>(&t_lds[nl][k]) = v;
  }
  // stage Wc1 (32x64) k-major
#pragma unroll
  for (int it = 0; it < 8; ++it) {
    int idx = it * 256 + tid;
    int j = idx >> 6;
    int k = idx & 63;
    w1_lds[k][j] = Wc1[(size_t)j * 64 + k];
  }
  if (tid < 64) w2_lds[tid] = Wc2[tid];
  else if (tid < 96) b1_lds[tid - 64] = bc1[tid - 64];
  else if (tid < 98) b2_lds[tid - 96] = bc2[tid - 96];
  __syncthreads();

  // c tile: tx 0..7 -> 4 outputs, ty 0..31 -> 2 nodes
  {
    const int tx = tid & 7, ty = tid >> 3;
    float4 a0c = make_float4(0.f, 0.f, 0.f, 0.f);
    float4 a1c = make_float4(0.f, 0.f, 0.f, 0.f);
#pragma unroll 4
    for (int k4 = 0; k4 < 16; ++k4) {
      float4 a0 = *reinterpret_cast<const float4*>(&t_lds[ty * 2 + 0][k4 * 4]);
      float4 a1 = *reinterpret_cast<const float4*>(&t_lds[ty * 2 + 1][k4 * 4]);
#pragma unroll
      for (int q = 0; q < 4; ++q) {
        float4 w = *reinterpret_cast<const float4*>(&w1_lds[k4 * 4 + q][tx * 4]);
        float a0q = reinterpret_cast<const float*>(&a0)[q];
        float a1q = reinterpret_cast<const float*>(&a1)[q];
        a0c.x = fmaf(a0q, w.x, a0c.x); a0c.y = fmaf(a0q, w.y, a0c.y);
        a0c.z = fmaf(a0q, w.z, a0c.z); a0c.w = fmaf(a0q, w.w, a0c.w);
        a1c.x = fmaf(a1q, w.x, a1c.x); a1c.y = fmaf(a1q, w.y, a1c.y);
        a1c.z = fmaf(a1q, w.z, a1c.z); a1c.w = fmaf(a1q, w.w, a1c.w);
      }
    }
    float4 b = *reinterpret_cast<const float4*>(&b1_lds[tx * 4]);
    a0c.x = fmaxf(a0c.x + b.x, 0.f); a0c.y = fmaxf(a0c.y + b.y, 0.f);
    a0c.z = fmaxf(a0c.z + b.z, 0.f); a0c.w = fmaxf(a0c.w + b.w, 0.f);
    a1c.x = fmaxf(a1c.x + b.x, 0.f); a1c.y = fmaxf(a1c.y + b.y, 0.f);
    a1c.z = fmaxf(a1c.z + b.z, 0.f); a1c.w = fmaxf(a1c.w + b.w, 0.f);
    *reinterpret_cast<float4*>(&c_lds[ty * 2 + 0][tx * 4]) = a0c;
    *reinterpret_cast<float4*>(&c_lds[ty * 2 + 1][tx * 4]) = a1c;
  }
  __syncthreads();

  if (tid < 128) {
    int nl = tid >> 1, o = tid & 1;
    int ng = nbase + nl;
    if (ng < N_NODES) {
      float s = b2_lds[o];
#pragma unroll
      for (int k = 0; k < 32; ++k) s = fmaf(c_lds[nl][k], w2_lds[o * 32 + k], s);
      out[(size_t)ng * 2 + o] = s;
    }
  }
}

// ---------------- launcher ----------------

extern "C" void kernel_launch(void* const* d_in, const int* in_sizes, int n_in,
                              void* d_out, int out_size, void* d_ws, size_t ws_size,
                              hipStream_t stream) {
  const float* x      = (const float*)d_in[0];
  const int*   ei     = (const int*)d_in[1];
  const float* ew     = (const float*)d_in[2];
  const float* W1rel  = (const float*)d_in[3];
  const float* W1root = (const float*)d_in[5];
  const float* W2rel  = (const float*)d_in[6];
  const float* W2root = (const float*)d_in[8];
  const float* W3rel  = (const float*)d_in[9];
  const float* W3root = (const float*)d_in[11];
  const float* g1  = (const float*)d_in[12];
  const float* be1 = (const float*)d_in[13];
  const float* g2  = (const float*)d_in[14];
  const float* be2 = (const float*)d_in[15];
  const float* g3  = (const float*)d_in[16];
  const float* be3 = (const float*)d_in[17];
  const float* Wc1 = (const float*)d_in[18];
  const float* bc1 = (const float*)d_in[19];
  const float* Wc2 = (const float*)d_in[20];
  const float* bc2 = (const float*)d_in[21];

  float* ws = (float*)d_ws;
  const size_t NF = (size_t)N_NODES * 64;
  float* A = ws;            // agg1 (N*32) -> agg2 (N*64) -> agg3 (N*64)
  float* B = ws + NF;       // h1pre -> y2 -> h3pre
  float* C = ws + 2 * NF;   // h1, live to the end
  float* E = ws + 3 * NF;   // h2pre / h2act in place (N*128)
  float* X = ws + 5 * NF;
  float* S = X;                               // 1024 floats BN stats
  int* rowptr  = (int*)(X + 1024);            // N+1
  int* cnt     = rowptr + (N_NODES + 2);      // N
  int* cursor  = cnt + N_NODES;               // N
  int* col_src = cursor + N_NODES;            // E
  float* col_w = (float*)(col_src + N_EDGES); // E
  // S: L1 sums@0(128) sc1@128 sh1@192; L2 sums@256(256) sc2@512 sh2@640;
  //    L3 sums@768(128) sc3@896 sh3@960

  hipMemsetAsync(S, 0, 1024 * sizeof(float), stream);
  hipMemsetAsync(cnt, 0, N_NODES * sizeof(int), stream);

  const int edgeBlocks = (N_EDGES + 255) / 256;
  const int tileBlocks = (N_NODES + 63) / 64;  // 1563

  // CSR build (by destination)
  hist_kernel<<<edgeBlocks, 256, 0, stream>>>(ei, cnt);
  scan_kernel<<<1, SCAN_T, 0, stream>>>(cnt, rowptr, cursor);
  fill_kernel<<<edgeBlocks, 256, 0, stream>>>(ei, ew, cursor, col_src, col_w);

  // ---- layer 1 ----
  gather_d32<<<(N_NODES * 8 + 255) / 256, 256, 0, stream>>>(x, rowptr, col_src, A);
  gemm_node<32, 32, 64, 0><<<tileBlocks, 256, 0, stream>>>(
      A, x, W1rel, W1root, nullptr, nullptr, nullptr, B, nullptr);  // h1pre -> B
  bn_stats<64><<<128, 256, 0, stream>>>(B, S);
  bn_finalize<<<1, 128, 0, stream>>>(S, g1, be1, S + 128, S + 192, 64);
  bn_apply_relu_d64<<<(int)((NF / 4 + 255) / 256), 256, 0, stream>>>(B, S + 128, S + 192, C);

  // ---- layer 2 ----
  gather_d64<false><<<(N_NODES * 16 + 255) / 256, 256, 0, stream>>>(C, rowptr, col_src, col_w, A);
  gemm_node<64, 64, 128, 0><<<tileBlocks, 256, 0, stream>>>(
      A, C, W2rel, W2root, nullptr, nullptr, nullptr, E, nullptr);  // h2pre -> E
  bn_stats<128><<<128, 256, 0, stream>>>(E, S + 256);
  bn_finalize<<<1, 128, 0, stream>>>(S + 256, g2, be2, S + 512, S + 640, 128);
  // y2 = relu(bn2(h2pre)) @ W3rel^T -> B ; h2act -> E (in place)
  gemm_node<128, 0, 64, 2><<<tileBlocks, 256, 0, stream>>>(
      E, nullptr, W3rel, nullptr, S + 512, S + 640, nullptr, B, E);

  // ---- layer 3 ----
  gather_d64<true><<<(N_NODES * 16 + 255) / 256, 256, 0, stream>>>(B, rowptr, col_src, col_w, A);
  gemm_node<128, 0, 64, 1><<<tileBlocks, 256, 0, stream>>>(
      E, nullptr, W3root, nullptr, nullptr, nullptr, A, B, nullptr);  // h3pre -> B
  bn_stats<64><<<128, 256, 0, stream>>>(B, S + 768);
  bn_finalize<<<1, 128, 0, stream>>>(S + 768, g3, be3, S + 896, S + 960, 64);

  // ---- residual + classifier ----
  final_fused<<<tileBlocks, 256, 0, stream>>>(B, C, S + 896, S + 960, Wc1, bc1, Wc2, bc2,
                                              (float*)d_out);
}

// Round 4
// 804.267 us; speedup vs baseline: 6.1330x; 1.2635x over previous
//
#include <hip/hip_runtime.h>

#define N_NODES 100000
#define N_EDGES 1600000
#define EPSV 1e-5f

// ---------------- CSR-by-destination build ----------------

__global__ void hist_kernel(const int* __restrict__ ei, int* __restrict__ cnt) {
  int e = blockIdx.x * blockDim.x + threadIdx.x;
  if (e >= N_EDGES) return;
  atomicAdd(&cnt[ei[N_EDGES + e]], 1);
}

// 3-phase device-wide exclusive scan of cnt[N_NODES] -> rowptr/cursor
#define SCAN_BLK 1024
#define SCAN_NB ((N_NODES + SCAN_BLK - 1) / SCAN_BLK)  // 98

__global__ void scan_phase1(const int* __restrict__ cnt, int* __restrict__ blocksum) {
  __shared__ int part[256];
  int base = blockIdx.x * SCAN_BLK + threadIdx.x * 4;
  int s = 0;
#pragma unroll
  for (int i = 0; i < 4; ++i) {
    int idx = base + i;
    if (idx < N_NODES) s += cnt[idx];
  }
  part[threadIdx.x] = s;
  __syncthreads();
  for (int d = 128; d > 0; d >>= 1) {
    if (threadIdx.x < d) part[threadIdx.x] += part[threadIdx.x + d];
    __syncthreads();
  }
  if (threadIdx.x == 0) blocksum[blockIdx.x] = part[0];
}

__global__ void scan_phase2(int* __restrict__ blocksum, int* __restrict__ rowptr) {
  __shared__ int part[128];
  int tid = threadIdx.x;
  int v = (tid < SCAN_NB) ? blocksum[tid] : 0;
  part[tid] = v;
  __syncthreads();
  for (int d = 1; d < 128; d <<= 1) {
    int t = (tid >= d) ? part[tid - d] : 0;
    __syncthreads();
    part[tid] += t;
    __syncthreads();
  }
  if (tid < SCAN_NB) blocksum[tid] = part[tid] - v;  // exclusive
  if (tid == 127) rowptr[N_NODES] = part[127];
}

__global__ void scan_phase3(const int* __restrict__ cnt, const int* __restrict__ blocksum,
                            int* __restrict__ rowptr, int* __restrict__ cursor) {
  __shared__ int part[256];
  int base = blockIdx.x * SCAN_BLK + threadIdx.x * 4;
  int c[4];
  int s = 0;
#pragma unroll
  for (int i = 0; i < 4; ++i) {
    int idx = base + i;
    c[i] = (idx < N_NODES) ? cnt[idx] : 0;
    s += c[i];
  }
  part[threadIdx.x] = s;
  __syncthreads();
  int me = s;
  for (int d = 1; d < 256; d <<= 1) {
    int t = (threadIdx.x >= d) ? part[threadIdx.x - d] : 0;
    __syncthreads();
    part[threadIdx.x] += t;
    __syncthreads();
  }
  int off = blocksum[blockIdx.x] + part[threadIdx.x] - me;
#pragma unroll
  for (int i = 0; i < 4; ++i) {
    int idx = base + i;
    if (idx < N_NODES) {
      rowptr[idx] = off;
      cursor[idx] = off;
      off += c[i];
    }
  }
}

__global__ void fill_kernel(const int* __restrict__ ei, const float* __restrict__ ew,
                            int* __restrict__ cursor, int* __restrict__ col_src,
                            float* __restrict__ col_w) {
  int e = blockIdx.x * blockDim.x + threadIdx.x;
  if (e >= N_EDGES) return;
  int d = ei[N_EDGES + e];
  int p = atomicAdd(&cursor[d], 1);
  col_src[p] = ei[e];
  col_w[p] = ew[e];
}

// ---------------- gather-side segment sums ----------------

__global__ void gather_d32(const float* __restrict__ x, const int* __restrict__ rowptr,
                           const int* __restrict__ col_src, float* __restrict__ agg) {
  int gid = blockIdx.x * blockDim.x + threadIdx.x;
  int n = gid >> 3;
  if (n >= N_NODES) return;
  int c = gid & 7;
  int beg = rowptr[n], end = rowptr[n + 1];
  float4 acc = make_float4(0.f, 0.f, 0.f, 0.f);
  for (int p = beg; p < end; ++p) {
    int src = col_src[p];
    float4 v = *reinterpret_cast<const float4*>(x + (size_t)src * 32 + c * 4);
    acc.x += v.x; acc.y += v.y; acc.z += v.z; acc.w += v.w;
  }
  *reinterpret_cast<float4*>(agg + (size_t)n * 32 + c * 4) = acc;
}

template <bool WEIGHTED>
__global__ void gather_d64(const float* __restrict__ h, const int* __restrict__ rowptr,
                           const int* __restrict__ col_src, const float* __restrict__ col_w,
                           float* __restrict__ agg) {
  int gid = blockIdx.x * blockDim.x + threadIdx.x;
  int n = gid >> 4;
  if (n >= N_NODES) return;
  int c = gid & 15;
  int beg = rowptr[n], end = rowptr[n + 1];
  float4 acc = make_float4(0.f, 0.f, 0.f, 0.f);
  for (int p = beg; p < end; ++p) {
    int src = col_src[p];
    float4 v = *reinterpret_cast<const float4*>(h + (size_t)src * 64 + c * 4);
    if (WEIGHTED) {
      float w = col_w[p];
      acc.x = fmaf(v.x, w, acc.x); acc.y = fmaf(v.y, w, acc.y);
      acc.z = fmaf(v.z, w, acc.z); acc.w = fmaf(v.w, w, acc.w);
    } else {
      acc.x += v.x; acc.y += v.y; acc.z += v.z; acc.w += v.w;
    }
  }
  *reinterpret_cast<float4*>(agg + (size_t)n * 64 + c * 4) = acc;
}

// ---------------- LDS-tiled node GEMM ----------------

template <int K1, int K2, int DO, int MODE>
__global__ __launch_bounds__(256) void gemm_node(
    const float* __restrict__ A1, const float* __restrict__ A2,
    const float* __restrict__ W1, const float* __restrict__ W2,
    const float* __restrict__ sc, const float* __restrict__ sh,
    const float* __restrict__ R, float* __restrict__ out,
    float* h2act) {
  constexpr int K = K1 + K2;
  constexpr int NC = K / 64;
  constexpr int NJB = DO / 64;
  __shared__ __align__(16) float A_lds[64][68];
  __shared__ __align__(16) float W_lds[64][DO + 4];

  const int tid = threadIdx.x;
  const int tx = tid & 15, ty = tid >> 4;
  const int nbase = blockIdx.x * 64;

  float4 acc[4][NJB];
#pragma unroll
  for (int i = 0; i < 4; ++i)
#pragma unroll
    for (int jb = 0; jb < NJB; ++jb) acc[i][jb] = make_float4(0.f, 0.f, 0.f, 0.f);

#pragma unroll 1
  for (int c = 0; c < NC; ++c) {
    const int kb = c * 64;
    if (c) __syncthreads();
#pragma unroll
    for (int it = 0; it < 4; ++it) {
      int idx = it * 256 + tid;
      int nl = idx >> 4;
      int kq = (idx & 15) * 4;
      int k = kb + kq;
      int ng = nbase + nl;
      float4 v = make_float4(0.f, 0.f, 0.f, 0.f);
      if (ng < N_NODES) {
        if (K2 == 0 || k < K1)
          v = *reinterpret_cast<const float4*>(A1 + (size_t)ng * K1 + k);
        else
          v = *reinterpret_cast<const float4*>(A2 + (size_t)ng * K2 + (k - K1));
      }
      if (MODE == 2) {
        float4 s4 = *reinterpret_cast<const float4*>(sc + k);
        float4 h4 = *reinterpret_cast<const float4*>(sh + k);
        v.x = fmaxf(fmaf(v.x, s4.x, h4.x), 0.f);
        v.y = fmaxf(fmaf(v.y, s4.y, h4.y), 0.f);
        v.z = fmaxf(fmaf(v.z, s4.z, h4.z), 0.f);
        v.w = fmaxf(fmaf(v.w, s4.w, h4.w), 0.f);
        if (ng < N_NODES)
          *reinterpret_cast<float4*>(h2act + (size_t)ng * K1 + k) = v;
      }
      *reinterpret_cast<float4*>(&A_lds[nl][kq]) = v;
    }
#pragma unroll
    for (int it = 0; it < DO / 4; ++it) {
      int idx = it * 256 + tid;
      int j = idx >> 6;
      int kl = idx & 63;
      int k = kb + kl;
      float w;
      if (K2 == 0 || k < K1) w = W1[(size_t)j * K1 + k];
      else w = W2[(size_t)j * K2 + (k - K1)];
      W_lds[kl][j] = w;
    }
    __syncthreads();
#pragma unroll 4
    for (int k4 = 0; k4 < 16; ++k4) {
      float4 a[4];
#pragma unroll
      for (int i = 0; i < 4; ++i)
        a[i] = *reinterpret_cast<const float4*>(&A_lds[ty * 4 + i][k4 * 4]);
#pragma unroll
      for (int q = 0; q < 4; ++q) {
#pragma unroll
        for (int jb = 0; jb < NJB; ++jb) {
          float4 w = *reinterpret_cast<const float4*>(&W_lds[k4 * 4 + q][jb * 64 + tx * 4]);
#pragma unroll
          for (int i = 0; i < 4; ++i) {
            float av = reinterpret_cast<const float*>(&a[i])[q];
            acc[i][jb].x = fmaf(av, w.x, acc[i][jb].x);
            acc[i][jb].y = fmaf(av, w.y, acc[i][jb].y);
            acc[i][jb].z = fmaf(av, w.z, acc[i][jb].z);
            acc[i][jb].w = fmaf(av, w.w, acc[i][jb].w);
          }
        }
      }
    }
  }
#pragma unroll
  for (int i = 0; i < 4; ++i) {
    int ng = nbase + ty * 4 + i;
    if (ng >= N_NODES) continue;
#pragma unroll
    for (int jb = 0; jb < NJB; ++jb) {
      float4 r = acc[i][jb];
      if (MODE == 1) {
        float4 rr = *reinterpret_cast<const float4*>(R + (size_t)ng * DO + jb * 64 + tx * 4);
        r.x += rr.x; r.y += rr.y; r.z += rr.z; r.w += rr.w;
      }
      *reinterpret_cast<float4*>(out + (size_t)ng * DO + jb * 64 + tx * 4) = r;
    }
  }
}

// ---------------- batchnorm ----------------

template <int D>
__global__ void bn_stats(const float* __restrict__ h, float* __restrict__ sums) {
  const int LANES = 256 / D;
  int j = threadIdx.x & (D - 1);
  int lane = threadIdx.x / D;
  float s = 0.f, ss = 0.f;
  for (int n = blockIdx.x * LANES + lane; n < N_NODES; n += gridDim.x * LANES) {
    float v = h[(size_t)n * D + j];
    s += v; ss += v * v;
  }
  unsafeAtomicAdd(&sums[j], s);
  unsafeAtomicAdd(&sums[D + j], ss);
}

__global__ void bn_finalize(const float* __restrict__ sums, const float* __restrict__ g,
                            const float* __restrict__ be, float* __restrict__ sc,
                            float* __restrict__ sh, int D) {
  int j = threadIdx.x;
  if (j >= D) return;
  const float invN = 1.f / (float)N_NODES;
  float mean = sums[j] * invN;
  float var = sums[D + j] * invN - mean * mean;
  float r = rsqrtf(var + EPSV);
  float scale = g[j] * r;
  sc[j] = scale;
  sh[j] = be[j] - mean * scale;
}

__global__ void bn_apply_relu_d64(const float* __restrict__ hp, const float* __restrict__ sc,
                                  const float* __restrict__ sh, float* __restrict__ h) {
  long long i4 = (long long)blockIdx.x * blockDim.x + threadIdx.x;
  if (i4 * 4 >= (long long)N_NODES * 64) return;
  int j0 = (int)((i4 * 4) & 63);
  float4 v = reinterpret_cast<const float4*>(hp)[i4];
  v.x = fmaxf(fmaf(v.x, sc[j0 + 0], sh[j0 + 0]), 0.f);
  v.y = fmaxf(fmaf(v.y, sc[j0 + 1], sh[j0 + 1]), 0.f);
  v.z = fmaxf(fmaf(v.z, sc[j0 + 2], sh[j0 + 2]), 0.f);
  v.w = fmaxf(fmaf(v.w, sc[j0 + 3], sh[j0 + 3]), 0.f);
  reinterpret_cast<float4*>(h)[i4] = v;
}

// ---------------- fused residual + classifier ----------------

__global__ __launch_bounds__(256) void final_fused(
    const float* __restrict__ h3p, const float* __restrict__ h1,
    const float* __restrict__ sc, const float* __restrict__ sh,
    const float* __restrict__ Wc1, const float* __restrict__ bc1,
    const float* __restrict__ Wc2, const float* __restrict__ bc2,
    float* __restrict__ out) {
  __shared__ __align__(16) float t_lds[64][68];
  __shared__ __align__(16) float w1_lds[64][36];
  __shared__ __align__(16) float c_lds[64][36];
  __shared__ __align__(16) float w2_lds[64];
  __shared__ __align__(16) float b1_lds[32];
  __shared__ float b2_lds[2];
  const int tid = threadIdx.x;
  const int nbase = blockIdx.x * 64;

#pragma unroll
  for (int it = 0; it < 4; ++it) {
    int idx = it * 256 + tid;
    int nl = idx >> 4;
    int k = (idx & 15) * 4;
    int ng = nbase + nl;
    float4 v = make_float4(0.f, 0.f, 0.f, 0.f);
    if (ng < N_NODES) {
      float4 p = *reinterpret_cast<const float4*>(h3p + (size_t)ng * 64 + k);
      float4 u = *reinterpret_cast<const float4*>(h1 + (size_t)ng * 64 + k);
      float4 s4 = *reinterpret_cast<const float4*>(sc + k);
      float4 h4 = *reinterpret_cast<const float4*>(sh + k);
      v.x = fmaxf(fmaf(p.x, s4.x, h4.x) + u.x, 0.f);
      v.y = fmaxf(fmaf(p.y, s4.y, h4.y) + u.y, 0.f);
      v.z = fmaxf(fmaf(p.z, s4.z, h4.z) + u.z, 0.f);
      v.w = fmaxf(fmaf(p.w, s4.w, h4.w) + u.w, 0.f);
    }
    *reinterpret_cast<float4*>(&t_lds[nl][k]) = v;
  }
#pragma unroll
  for (int it = 0; it < 8; ++it) {
    int idx = it * 256 + tid;
    int j = idx >> 6;
    int k = idx & 63;
    w1_lds[k][j] = Wc1[(size_t)j * 64 + k];
  }
  if (tid < 64) w2_lds[tid] = Wc2[tid];
  else if (tid < 96) b1_lds[tid - 64] = bc1[tid - 64];
  else if (tid < 98) b2_lds[tid - 96] = bc2[tid - 96];
  __syncthreads();

  {
    const int tx = tid & 7, ty = tid >> 3;
    float4 a0c = make_float4(0.f, 0.f, 0.f, 0.f);
    float4 a1c = make_float4(0.f, 0.f, 0.f, 0.f);
#pragma unroll 4
    for (int k4 = 0; k4 < 16; ++k4) {
      float4 a0 = *reinterpret_cast<const float4*>(&t_lds[ty * 2 + 0][k4 * 4]);
      float4 a1 = *reinterpret_cast<const float4*>(&t_lds[ty * 2 + 1][k4 * 4]);
#pragma unroll
      for (int q = 0; q < 4; ++q) {
        float4 w = *reinterpret_cast<const float4*>(&w1_lds[k4 * 4 + q][tx * 4]);
        float a0q = reinterpret_cast<const float*>(&a0)[q];
        float a1q = reinterpret_cast<const float*>(&a1)[q];
        a0c.x = fmaf(a0q, w.x, a0c.x); a0c.y = fmaf(a0q, w.y, a0c.y);
        a0c.z = fmaf(a0q, w.z, a0c.z); a0c.w = fmaf(a0q, w.w, a0c.w);
        a1c.x = fmaf(a1q, w.x, a1c.x); a1c.y = fmaf(a1q, w.y, a1c.y);
        a1c.z = fmaf(a1q, w.z, a1c.z); a1c.w = fmaf(a1q, w.w, a1c.w);
      }
    }
    float4 b = *reinterpret_cast<const float4*>(&b1_lds[tx * 4]);
    a0c.x = fmaxf(a0c.x + b.x, 0.f); a0c.y = fmaxf(a0c.y + b.y, 0.f);
    a0c.z = fmaxf(a0c.z + b.z, 0.f); a0c.w = fmaxf(a0c.w + b.w, 0.f);
    a1c.x = fmaxf(a1c.x + b.x, 0.f); a1c.y = fmaxf(a1c.y + b.y, 0.f);
    a1c.z = fmaxf(a1c.z + b.z, 0.f); a1c.w = fmaxf(a1c.w + b.w, 0.f);
    *reinterpret_cast<float4*>(&c_lds[ty * 2 + 0][tx * 4]) = a0c;
    *reinterpret_cast<float4*>(&c_lds[ty * 2 + 1][tx * 4]) = a1c;
  }
  __syncthreads();

  if (tid < 128) {
    int nl = tid >> 1, o = tid & 1;
    int ng = nbase + nl;
    if (ng < N_NODES) {
      float s = b2_lds[o];
#pragma unroll
      for (int k = 0; k < 32; ++k) s = fmaf(c_lds[nl][k], w2_lds[o * 32 + k], s);
      out[(size_t)ng * 2 + o] = s;
    }
  }
}

// ---------------- launcher ----------------

extern "C" void kernel_launch(void* const* d_in, const int* in_sizes, int n_in,
                              void* d_out, int out_size, void* d_ws, size_t ws_size,
                              hipStream_t stream) {
  const float* x      = (const float*)d_in[0];
  const int*   ei     = (const int*)d_in[1];
  const float* ew     = (const float*)d_in[2];
  const float* W1rel  = (const float*)d_in[3];
  const float* W1root = (const float*)d_in[5];
  const float* W2rel  = (const float*)d_in[6];
  const float* W2root = (const float*)d_in[8];
  const float* W3rel  = (const float*)d_in[9];
  const float* W3root = (const float*)d_in[11];
  const float* g1  = (const float*)d_in[12];
  const float* be1 = (const float*)d_in[13];
  const float* g2  = (const float*)d_in[14];
  const float* be2 = (const float*)d_in[15];
  const float* g3  = (const float*)d_in[16];
  const float* be3 = (const float*)d_in[17];
  const float* Wc1 = (const float*)d_in[18];
  const float* bc1 = (const float*)d_in[19];
  const float* Wc2 = (const float*)d_in[20];
  const float* bc2 = (const float*)d_in[21];

  float* ws = (float*)d_ws;
  const size_t NF = (size_t)N_NODES * 64;
  float* A = ws;            // agg1 (N*32) -> agg2 (N*64) -> agg3 (N*64)
  float* B = ws + NF;       // h1pre -> y2 -> h3pre
  float* C = ws + 2 * NF;   // h1, live to the end
  float* E = ws + 3 * NF;   // h2pre / h2act in place (N*128)
  float* X = ws + 5 * NF;
  float* S = X;                               // 1024 floats BN stats
  int* rowptr  = (int*)(X + 1024);            // N+1
  int* cnt     = rowptr + (N_NODES + 2);      // N
  int* cursor  = cnt + N_NODES;               // N
  int* blocksum= cursor + N_NODES;            // SCAN_NB (pad 128)
  int* col_src = blocksum + 128;              // E
  float* col_w = (float*)(col_src + N_EDGES); // E

  hipMemsetAsync(S, 0, 1024 * sizeof(float), stream);
  hipMemsetAsync(cnt, 0, N_NODES * sizeof(int), stream);

  const int edgeBlocks = (N_EDGES + 255) / 256;
  const int tileBlocks = (N_NODES + 63) / 64;  // 1563

  // CSR build (by destination)
  hist_kernel<<<edgeBlocks, 256, 0, stream>>>(ei, cnt);
  scan_phase1<<<SCAN_NB, 256, 0, stream>>>(cnt, blocksum);
  scan_phase2<<<1, 128, 0, stream>>>(blocksum, rowptr);
  scan_phase3<<<SCAN_NB, 256, 0, stream>>>(cnt, blocksum, rowptr, cursor);
  fill_kernel<<<edgeBlocks, 256, 0, stream>>>(ei, ew, cursor, col_src, col_w);

  // ---- layer 1 ----
  gather_d32<<<(N_NODES * 8 + 255) / 256, 256, 0, stream>>>(x, rowptr, col_src, A);
  gemm_node<32, 32, 64, 0><<<tileBlocks, 256, 0, stream>>>(
      A, x, W1rel, W1root, nullptr, nullptr, nullptr, B, nullptr);
  bn_stats<64><<<128, 256, 0, stream>>>(B, S);
  bn_finalize<<<1, 128, 0, stream>>>(S, g1, be1, S + 128, S + 192, 64);
  bn_apply_relu_d64<<<(int)((NF / 4 + 255) / 256), 256, 0, stream>>>(B, S + 128, S + 192, C);

  // ---- layer 2 ----
  gather_d64<false><<<(N_NODES * 16 + 255) / 256, 256, 0, stream>>>(C, rowptr, col_src, col_w, A);
  gemm_node<64, 64, 128, 0><<<tileBlocks, 256, 0, stream>>>(
      A, C, W2rel, W2root, nullptr, nullptr, nullptr, E, nullptr);
  bn_stats<128><<<128, 256, 0, stream>>>(E, S + 256);
  bn_finalize<<<1, 128, 0, stream>>>(S + 256, g2, be2, S + 512, S + 640, 128);
  gemm_node<128, 0, 64, 2><<<tileBlocks, 256, 0, stream>>>(
      E, nullptr, W3rel, nullptr, S + 512, S + 640, nullptr, B, E);

  // ---- layer 3 ----
  gather_d64<true><<<(N_NODES * 16 + 255) / 256, 256, 0, stream>>>(B, rowptr, col_src, col_w, A);
  gemm_node<128, 0, 64, 1><<<tileBlocks, 256, 0, stream>>>(
      E, nullptr, W3root, nullptr, nullptr, nullptr, A, B, nullptr);
  bn_stats<64><<<128, 256, 0, stream>>>(B, S + 768);
  bn_finalize<<<1, 128, 0, stream>>>(S + 768, g3, be3, S + 896, S + 960, 64);

  // ---- residual + classifier ----
  final_fused<<<tileBlocks, 256, 0, stream>>>(B, C, S + 896, S + 960, Wc1, bc1, Wc2, bc2,
                                              (float*)d_out);
}